// Round 1
// baseline (767.717 us; speedup 1.0000x reference)
//
#include <hip/hip_runtime.h>
#include <hip/hip_bf16.h>

// Problem constants (MindSpeedTEGroupedLinear: 64 experts, column-parallel)
#define E_ 64
#define K_ 2048
#define N_ 1408
#define TOKENS_ 32768
#define BM 128
#define BN 128
#define BK 64
#define NK (K_ / BK)   // 32
#define NTHREADS 512
#define MT_MAX (TOKENS_ / BM + E_)   // 320 worst-case M-tiles

using f32x4  = __attribute__((ext_vector_type(4))) float;
using bf16x8 = __attribute__((ext_vector_type(8))) short;

__device__ __forceinline__ short f2b(float f) {
  __hip_bfloat16 h = __float2bfloat16(f);   // RNE; compiler fuses pairs to v_cvt_pk_bf16_f32
  return __builtin_bit_cast(short, h);
}

// Build per-M-tile table from m_splits: {expert, global_row0, rows_in_tile, pad}
__global__ void build_tiles(const int* __restrict__ m_splits, int4* __restrict__ table,
                            int* __restrict__ count) {
  if (threadIdx.x == 0 && blockIdx.x == 0) {
    int off = 0, t = 0;
    for (int e = 0; e < E_; ++e) {
      int m = m_splits[e];
      for (int r = 0; r < m; r += BM) {
        table[t] = make_int4(e, off + r, min(BM, m - r), 0);
        ++t;
      }
      off += m;
    }
    *count = t;
  }
}

__global__ __launch_bounds__(NTHREADS, 4) void gemm_grouped(
    const float* __restrict__ x, const float* __restrict__ W,
    const int4* __restrict__ table, const int* __restrict__ count,
    float* __restrict__ out) {
  // [buf][A|B][128 rows][64 k] bf16, XOR-swizzled within each row. 64 KiB.
  __shared__ char smem[2 * 2 * BM * BK * 2];

  const int mt = blockIdx.y;
  if (mt >= *count) return;
  const int4 te = table[mt];
  const int expert = te.x, row0 = te.y, nrows = te.z;
  const int n0 = blockIdx.x * BN;

  const int tid  = threadIdx.x;
  const int lane = tid & 63;
  const int w    = tid >> 6;   // 8 waves
  const int wm   = w >> 2;     // 0..1  (64-row stripe)
  const int wn   = w & 3;      // 0..3  (32-col stripe)

  // staging: 2 chunks/thread/tile, chunk = 8 consecutive k-floats of one row
  int srow[2], skc[2];
  srow[0] = tid >> 3;                skc[0] = tid & 7;
  srow[1] = (tid + NTHREADS) >> 3;   skc[1] = (tid + NTHREADS) & 7;

  const float* xrow = x + (size_t)row0 * K_;
  const float* wrow = W + (size_t)expert * (size_t)N_ * K_ + (size_t)n0 * K_;

  f32x4 sa[2][2], sb[2][2];
  const f32x4 zero4 = {0.f, 0.f, 0.f, 0.f};

  auto load_tiles = [&](int kt) {
    const int kbase = kt * BK;
#pragma unroll
    for (int c = 0; c < 2; ++c) {
      const int r = srow[c], kc = skc[c];
      if (r < nrows) {
        const float* p = xrow + (size_t)r * K_ + kbase + kc * 8;
        sa[c][0] = *(const f32x4*)p;
        sa[c][1] = *(const f32x4*)(p + 4);
      } else {
        sa[c][0] = zero4; sa[c][1] = zero4;
      }
      const float* q = wrow + (size_t)r * K_ + kbase + kc * 8;
      sb[c][0] = *(const f32x4*)q;
      sb[c][1] = *(const f32x4*)(q + 4);
    }
  };

  auto write_lds = [&](int buf) {
    const int base = buf * 32768;
#pragma unroll
    for (int c = 0; c < 2; ++c) {
      const int r = srow[c], kc = skc[c];
      const int off = r * 128 + ((kc * 16) ^ ((r & 7) << 4));  // swizzled 16B slot
      bf16x8 va, vb;
#pragma unroll
      for (int i = 0; i < 4; ++i) { va[i] = f2b(sa[c][0][i]); va[i + 4] = f2b(sa[c][1][i]); }
#pragma unroll
      for (int i = 0; i < 4; ++i) { vb[i] = f2b(sb[c][0][i]); vb[i + 4] = f2b(sb[c][1][i]); }
      *(bf16x8*)(smem + base + off)         = va;
      *(bf16x8*)(smem + base + 16384 + off) = vb;
    }
  };

  f32x4 acc[4][2];
#pragma unroll
  for (int i = 0; i < 4; ++i)
#pragma unroll
    for (int j = 0; j < 2; ++j) acc[i][j] = zero4;

  const int arow = wm * 64 + (lane & 15);
  const int brow = wn * 32 + (lane & 15);
  const int kb   = (lane >> 4) * 16;  // byte offset of this lane's 8-elem k-group

  auto compute = [&](int buf) {
    const int base = buf * 32768;
#pragma unroll
    for (int ks = 0; ks < 2; ++ks) {
      bf16x8 af[4], bfr[2];
#pragma unroll
      for (int i = 0; i < 4; ++i) {
        const int row = arow + i * 16;
        const int off = row * 128 + (((ks * 64) + kb) ^ ((row & 7) << 4));
        af[i] = *(const bf16x8*)(smem + base + off);
      }
#pragma unroll
      for (int j = 0; j < 2; ++j) {
        const int row = brow + j * 16;
        const int off = row * 128 + (((ks * 64) + kb) ^ ((row & 7) << 4));
        bfr[j] = *(const bf16x8*)(smem + base + 16384 + off);
      }
#pragma unroll
      for (int i = 0; i < 4; ++i)
#pragma unroll
        for (int j = 0; j < 2; ++j)
          acc[i][j] = __builtin_amdgcn_mfma_f32_16x16x32_bf16(af[i], bfr[j], acc[i][j], 0, 0, 0);
    }
  };

  // T14 2-phase: issue next tile's global loads before computing current tile
  load_tiles(0);
  write_lds(0);
  int cur = 0;
  for (int kt = 0; kt < NK; ++kt) {
    if (kt + 1 < NK) load_tiles(kt + 1);
    __syncthreads();               // prior ds_writes visible to all waves
    compute(cur);
    if (kt + 1 < NK) write_lds(cur ^ 1);   // other buffer: no WAR with current reads
    cur ^= 1;
  }

  // epilogue: C/D layout col=lane&15, row=(lane>>4)*4+reg
  const int crow = wm * 64 + (lane >> 4) * 4;
  const int ccol = n0 + wn * 32 + (lane & 15);
#pragma unroll
  for (int i = 0; i < 4; ++i) {
#pragma unroll
    for (int rr = 0; rr < 4; ++rr) {
      const int lr = crow + i * 16 + rr;
      if (lr < nrows) {
#pragma unroll
        for (int j = 0; j < 2; ++j)
          out[(size_t)(row0 + lr) * N_ + ccol + j * 16] = acc[i][j][rr];
      }
    }
  }
}

extern "C" void kernel_launch(void* const* d_in, const int* in_sizes, int n_in,
                              void* d_out, int out_size, void* d_ws, size_t ws_size,
                              hipStream_t stream) {
  const float* x        = (const float*)d_in[0];
  const float* W        = (const float*)d_in[1];
  const int*   m_splits = (const int*)d_in[2];
  float*       out      = (float*)d_out;

  int*  count = (int*)d_ws;
  int4* table = (int4*)((char*)d_ws + 16);

  build_tiles<<<1, 64, 0, stream>>>(m_splits, table, count);

  dim3 grid(N_ / BN, MT_MAX);
  gemm_grouped<<<grid, NTHREADS, 0, stream>>>(x, W, table, count, out);
}